// Round 8
// baseline (191.710 us; speedup 1.0000x reference)
//
#include <hip/hip_runtime.h>
#include <math.h>
#include <stdint.h>

#define B_DIM 4
#define C_DIM 256
#define N_DIM 2048
#define H_DIM 8
#define HD    64
#define HB    32                 // H*B
#define NTOK  (B_DIM * N_DIM)    // 8192
#define LOG2E 1.44269504f

typedef __attribute__((ext_vector_type(8))) short bf16x8;
typedef __attribute__((ext_vector_type(4))) float f32x4;
typedef __attribute__((ext_vector_type(16))) float f32x16;
typedef __attribute__((ext_vector_type(4))) unsigned u32x4;

static __device__ __forceinline__ short f2bf(float f) {          // RNE (cold paths)
    unsigned u = __builtin_bit_cast(unsigned, f);
    u += 0x7fffu + ((u >> 16) & 1u);
    return (short)(u >> 16);
}
static __device__ __forceinline__ float bf2f(short s) {
    unsigned u = ((unsigned)(unsigned short)s) << 16;
    return __builtin_bit_cast(float, u);
}
// raw v_exp_f32: exact for |x| <~ 126, skips OCML's range-guard sequence
static __device__ __forceinline__ float fx2(float x) {
#if __has_builtin(__builtin_amdgcn_exp2f)
    return __builtin_amdgcn_exp2f(x);
#else
    return exp2f(x);
#endif
}
// pack two fp32 -> two bf16 in one dword (HW packed cvt when available)
static __device__ __forceinline__ unsigned pk_bf16(float a, float b) {
#if __has_builtin(__builtin_amdgcn_cvt_pk_bf16_f32)
    auto v = __builtin_amdgcn_cvt_pk_bf16_f32(a, b);
    return __builtin_bit_cast(unsigned, v);
#else
    unsigned ua = __builtin_bit_cast(unsigned, a);
    unsigned ub = __builtin_bit_cast(unsigned, b);
    return ((ua + 0x8000u) >> 16) | ((ub + 0x8000u) & 0xffff0000u);
#endif
}
// permlane32_swap "unzip": a' = {a.lo | b.lo-in-hi}, b' = {a.hi-in-lo | b.hi}
static __device__ __forceinline__ void pl32swap(unsigned &a, unsigned &b) {
#if __has_builtin(__builtin_amdgcn_permlane32_swap)
    typedef __attribute__((ext_vector_type(2))) int i32x2_t;
    i32x2_t r = __builtin_amdgcn_permlane32_swap((int)a, (int)b, false, false);
    a = (unsigned)r[0]; b = (unsigned)r[1];
#else
    unsigned sa = __shfl_xor(a, 32), sb = __shfl_xor(b, 32);
    bool hi = (threadIdx.x & 32) != 0;
    unsigned na = hi ? sb : a;
    unsigned nb = hi ? b : sa;
    a = na; b = nb;
#endif
}

// async global->LDS 16B/lane: dest = wave-uniform LDS base + lane*16,
// src = per-lane global address. Fallback: plain reg round-trip.
static __device__ __forceinline__ void gll16(const void* g, void* ldsbase, int lane) {
#if __has_builtin(__builtin_amdgcn_global_load_lds)
    __builtin_amdgcn_global_load_lds(
        (const __attribute__((address_space(1))) void*)(uintptr_t)(g),
        (__attribute__((address_space(3))) void*)(uintptr_t)(ldsbase), 16, 0, 0);
#else
    *(bf16x8*)((char*)ldsbase + lane * 16) = *(const bf16x8*)g;
#endif
}

#define MFMA16(A, Bv, Cv) __builtin_amdgcn_mfma_f32_16x16x32_bf16(A, Bv, Cv, 0, 0, 0)
#define MFMA32(A, Bv, Cv) __builtin_amdgcn_mfma_f32_32x32x16_bf16(A, Bv, Cv, 0, 0, 0)

// 16x16 fragment layouts (proj_all staging, unchanged):
//   XS/YS(rt, ks, lane, j) = X[tok = rt*16+(lane&15)][c = ks*32+(lane>>4)*8+j]
//   WS(ot, ks, lane, j)    = W[o  = ot*16+(lane&15)][c = ks*32+(lane>>4)*8+j]
// 32x32x16 fragment layouts (attention kernels; frag = 1 KB, row=lane&31,
// k = (lane>>5)*8 + j):
//   QS/KS frag(hb, nt2, ks): M[n = nt2*32+(lane&31)][d = ks*16+(lane>>5)*8+j]
//     (QS holds Q * log2e); frag index = (hb*64 + nt2)*4 + ks
//   VS frag(hb, nb, nk, dt2): V[d = dt2*32+(lane&31)][n = nb*64+nk*16+(lane>>5)*8+j]
//     frag index = ((hb*32 + nb)*4 + nk)*2 + dt2

// ---------------------------------------------------------------------------
// cast+transpose to fragment-major (z 0..7: x/y batches) + weights (z == 8)
// ---------------------------------------------------------------------------
__global__ __launch_bounds__(256) void cast_all(
    const float* __restrict__ X, const float* __restrict__ Y,
    const float* __restrict__ Wq, const float* __restrict__ Wk,
    const float* __restrict__ Wv, const float* __restrict__ Wp,
    short* __restrict__ XS, short* __restrict__ YS,
    short* __restrict__ WSx, short* __restrict__ WSy)
{
    const int z = blockIdx.z;
    const int t = threadIdx.x;

    if (z == 8) {   // ---- weights: Wq -> WSx (256 chunks); Wk|Wv|Wp -> WSy (544) ----
        int base = (blockIdx.y * 32 + blockIdx.x) * 256 + t;   // 0..32767
#pragma unroll
        for (int rep = 0; rep < 2; ++rep) {
            int gid = base + rep * 32768;                       // 0..65535
            if (gid >= 51200) break;
            int lane = gid & 63, chunk = gid >> 6;              // chunk 0..799
            int lo = lane & 15, quad = lane >> 4;
            const float* src; short* dst;
            if (chunk < 256) {
                int ot = chunk >> 3, ks = chunk & 7;
                src = Wq + (size_t)(ot * 16 + lo) * C_DIM + ks * 32 + quad * 8;
                dst = WSx + (size_t)chunk * 512 + lane * 8;
            } else {
                int ch = chunk - 256;
                int ot = ch >> 3, ks = ch & 7;
                int row = ot * 16 + lo;
                const float* basep = (row < 512) ? (Wk + (size_t)row * C_DIM)
                                   : (row < 1024) ? (Wv + (size_t)(row - 512) * C_DIM)
                                                  : (Wp + (size_t)(row - 1024) * C_DIM);
                src = basep + ks * 32 + quad * 8;
                dst = WSy + (size_t)ch * 512 + lane * 8;
            }
            bf16x8 o;
#pragma unroll
            for (int j = 0; j < 8; ++j) o[j] = f2bf(src[j]);
            *(bf16x8*)dst = o;
        }
        return;
    }

    const float* src = (z < 4) ? X : Y;
    short* dst = (z < 4) ? XS : YS;
    const int b = z & 3, c0 = blockIdx.y * 64, n0 = blockIdx.x * 64;
    __shared__ float L[64][65];   // [c_local][n_local]
    for (int i = t; i < 4096; i += 256) {
        int cc = i >> 6, nn = i & 63;
        L[cc][nn] = src[((size_t)b * C_DIM + c0 + cc) * N_DIM + n0 + nn];
    }
    __syncthreads();
#pragma unroll
    for (int half = 0; half < 2; ++half) {
        int cid = half * 256 + t;
        int lane = cid & 63, fi = cid >> 6;      // fi 0..7
        int ksl = fi & 1, rtl = fi >> 1;         // rtl 0..3
        int lo = lane & 15, quad = lane >> 4;
        bf16x8 o;
#pragma unroll
        for (int j = 0; j < 8; ++j) o[j] = f2bf(L[ksl * 32 + quad * 8 + j][rtl * 16 + lo]);
        int rt = b * 128 + (n0 >> 4) + rtl;
        int ks = (c0 >> 5) + ksl;
        *(bf16x8*)(dst + ((size_t)(rt * 8 + ks) * 64 + lane) * 8) = o;
    }
}

// ---------------------------------------------------------------------------
// Merged MFMA projection (16x16 MFMA internally).
// oy<8: Q=(Wq x + bq)*log2e -> QS32. oy 8..15: K -> KS32. oy 16..23: V -> VS32u.
// oy==24: YP fp32 (b,n,d). Epilogues gather 32x32x16 fragments from LDS.
// ---------------------------------------------------------------------------
__global__ __launch_bounds__(256) void proj_all(
    const short* __restrict__ WSx, const short* __restrict__ WSy,
    const short* __restrict__ XS, const short* __restrict__ YS,
    const float* __restrict__ bq, const float* __restrict__ bk,
    const float* __restrict__ bv,
    short* __restrict__ QS, short* __restrict__ KS,
    short* __restrict__ VSu, float* __restrict__ Yo)
{
    const int oy = blockIdx.y;
    const bool isq = oy < 8;
    const short* WS = isq ? WSx : WSy;
    const short* Xs = isq ? XS : YS;
    const int oyl = isq ? oy : oy - 8;
    const int o0 = oyl * 64;
    const int tok0 = blockIdx.x * 128;
    const int t = threadIdx.x, wave = t >> 6, lane = t & 63;
    const int lo = lane & 15, quad = lane >> 4;

    __shared__ __align__(16) char smem[34816];

    const int ot = oyl * 4 + wave;
    const int rt0 = tok0 >> 4;
    const f32x4 czero = {0.f, 0.f, 0.f, 0.f};

    f32x4 acc[8];
#pragma unroll
    for (int i = 0; i < 8; ++i) acc[i] = czero;

#pragma unroll 2
    for (int ks = 0; ks < 8; ++ks) {
        bf16x8 a = *(const bf16x8*)(WS + ((size_t)(ot * 8 + ks) * 64 + lane) * 8);
#pragma unroll
        for (int nt = 0; nt < 8; ++nt) {
            bf16x8 bx = *(const bf16x8*)(Xs + ((size_t)((rt0 + nt) * 8 + ks) * 64 + lane) * 8);
            acc[nt] = MFMA16(a, bx, acc[nt]);
        }
    }

    const int b = tok0 >> 11;
    const int n0b = tok0 & (N_DIM - 1);

    if (oy < 16) {
        // ---- Q or K: T[128][72] bf16 -> 32x32 fragment-major QS/KS ----
        short* T = (short*)smem;
        const float* bias = isq ? bq : bk;
        const float scale = isq ? LOG2E : 1.f;
        float bvr[4];
#pragma unroll
        for (int r = 0; r < 4; ++r) bvr[r] = bias[o0 + wave * 16 + quad * 4 + r];
#pragma unroll
        for (int nt = 0; nt < 8; ++nt) {
            short4 pk;
            pk.x = f2bf((acc[nt][0] + bvr[0]) * scale);
            pk.y = f2bf((acc[nt][1] + bvr[1]) * scale);
            pk.z = f2bf((acc[nt][2] + bvr[2]) * scale);
            pk.w = f2bf((acc[nt][3] + bvr[3]) * scale);
            *(short4*)(T + (nt * 16 + lo) * 72 + wave * 16 + quad * 4) = pk;
        }
        __syncthreads();
        const int h = oyl;
        const int hb = h * 4 + b;
        short* dst = isq ? QS : KS;
#pragma unroll
        for (int s = 0; s < 4; ++s) {
            int cid = s * 256 + t;
            int ln = cid & 63, fi = cid >> 6;     // fi 0..15
            int ks = fi & 3, nt2l = fi >> 2;      // 4 d-chunks x 4 n-tiles
            bf16x8 v = *(const bf16x8*)(T + (nt2l * 32 + (ln & 31)) * 72
                                          + ks * 16 + ((ln >> 5) << 3));
            size_t frag = ((size_t)(hb * 64) + (n0b >> 5) + nt2l) * 4 + ks;
            *(bf16x8*)(dst + frag * 512 + ln * 8) = v;
        }
    } else if (oy < 24) {
        // ---- V: T2[64][136] bf16 (d-major) -> 32x32 fragment-major VSu ----
        short* T2 = (short*)smem;
        float bvr[4];
#pragma unroll
        for (int r = 0; r < 4; ++r) bvr[r] = bv[o0 - 512 + wave * 16 + quad * 4 + r];
#pragma unroll
        for (int nt = 0; nt < 8; ++nt)
#pragma unroll
            for (int r = 0; r < 4; ++r) {
                int ol = wave * 16 + quad * 4 + r;
                T2[ol * 136 + nt * 16 + lo] = f2bf(acc[nt][r] + bvr[r]);
            }
        __syncthreads();
        const int h = oy - 16;
        const int hb = h * 4 + b;
#pragma unroll
        for (int s = 0; s < 4; ++s) {
            int cid = s * 256 + t;
            int ln = cid & 63, fi = cid >> 6;     // fi 0..15
            int dt2 = fi & 1, nk = (fi >> 1) & 3, nbl = fi >> 3;
            bf16x8 v = *(const bf16x8*)(T2 + (dt2 * 32 + (ln & 31)) * 136
                                           + nbl * 64 + nk * 16 + ((ln >> 5) << 3));
            size_t frag = (((size_t)(hb * 32) + (n0b >> 6) + nbl) * 4 + nk) * 2 + dt2;
            *(bf16x8*)(VSu + frag * 512 + ln * 8) = v;
        }
    } else {
        // ---- YP: T3[128][68] fp32 -> (b,n,d) float4 stores ----
        float* T3 = (float*)smem;
#pragma unroll
        for (int nt = 0; nt < 8; ++nt) {
            float4 f;
            f.x = acc[nt][0]; f.y = acc[nt][1]; f.z = acc[nt][2]; f.w = acc[nt][3];
            *(float4*)(T3 + (nt * 16 + lo) * 68 + wave * 16 + quad * 4) = f;
        }
        __syncthreads();
#pragma unroll
        for (int s = 0; s < 8; ++s) {
            int cid = s * 256 + t;
            int row = cid >> 4, c4 = (cid & 15) * 4;
            float4 f = *(const float4*)(T3 + row * 68 + c4);
            *(float4*)(Yo + ((size_t)(tok0 + row)) * 64 + c4) = f;
        }
    }
}

// ---------------------------------------------------------------------------
// rowsum partials over m-QUARTERS, 32x32x16 MFMA, register-only (no LDS).
// Wave owns 64 n (8 Q frags resident); streams K m-tiles from L2.
// 1024 blocks x 256 thr. Quarters 0,1 -> RSp; 2,3 -> RSpW (weight overlay).
// ---------------------------------------------------------------------------
__global__ __launch_bounds__(256, 4) void rowsum_mfma(
    const short* __restrict__ QS, const short* __restrict__ KS,
    float* __restrict__ RSp, float* __restrict__ RSpW)
{
    const int id = blockIdx.x;                     // 1024 blocks
    const int hb = ((id & 7) << 2) | ((id >> 3) & 3);   // h = id&7 -> XCD L2 locality
    const int zq = (id >> 5) & 3;                  // m-quarter
    const int n0 = (id >> 7) * 256;                // 8 n-tiles
    const int t = threadIdx.x, wave = t >> 6, lane = t & 63;
    const int hi = lane >> 5;
    f32x16 czero16;
#pragma unroll
    for (int r = 0; r < 16; ++r) czero16[r] = 0.f;

    bf16x8 qf[2][4];
    const short* qb = QS + ((size_t)(hb * 64 + (n0 >> 5) + wave * 2)) * 4 * 512 + lane * 8;
#pragma unroll
    for (int tt = 0; tt < 2; ++tt)
#pragma unroll
        for (int ks = 0; ks < 4; ++ks)
            qf[tt][ks] = *(const bf16x8*)(qb + (tt * 4 + ks) * 512);

    float sm[2][16];
#pragma unroll
    for (int tt = 0; tt < 2; ++tt)
#pragma unroll
        for (int r = 0; r < 16; ++r) sm[tt][r] = 0.f;

    const short* kp = KS + ((size_t)(hb * 64 + zq * 16)) * 4 * 512 + lane * 8;
    for (int mt = 0; mt < 16; ++mt) {
        bf16x8 kf[4];
#pragma unroll
        for (int ks = 0; ks < 4; ++ks)
            kf[ks] = *(const bf16x8*)(kp + (mt * 4 + ks) * 512);
#pragma unroll
        for (int tt = 0; tt < 2; ++tt) {
            f32x16 cc = czero16;
#pragma unroll
            for (int ks = 0; ks < 4; ++ks) cc = MFMA32(qf[tt][ks], kf[ks], cc);
#pragma unroll
            for (int r = 0; r < 16; ++r) sm[tt][r] += fx2(cc[r]);
        }
    }

#pragma unroll
    for (int sft = 1; sft < 32; sft <<= 1)
#pragma unroll
        for (int tt = 0; tt < 2; ++tt)
#pragma unroll
            for (int r = 0; r < 16; ++r) sm[tt][r] += __shfl_xor(sm[tt][r], sft);

    if ((lane & 31) == 0) {
        float* dst = (zq < 2) ? (RSp  + (size_t)zq * HB * N_DIM)
                              : (RSpW + (size_t)(zq - 2) * HB * N_DIM);
#pragma unroll
        for (int tt = 0; tt < 2; ++tt)
#pragma unroll
            for (int g = 0; g < 4; ++g) {
                int n = n0 + wave * 64 + tt * 32 + g * 8 + hi * 4;
                float4 v = {sm[tt][g * 4 + 0], sm[tt][g * 4 + 1],
                            sm[tt][g * 4 + 2], sm[tt][g * 4 + 3]};
                *(float4*)(dst + (size_t)hb * N_DIM + n) = v;
            }
    }
}

// ---------------------------------------------------------------------------
// VS = VSu * 1/(sum of 4 rowsum partials) — 32x32 fragment layout in/out
// ---------------------------------------------------------------------------
__global__ __launch_bounds__(256) void v_scale(
    const short* __restrict__ VSu, const float* __restrict__ RSp,
    const float* __restrict__ RSpW, short* __restrict__ VS)
{
    int t = blockIdx.x * 256 + threadIdx.x;     // 0..524287
    int lane = t & 63, fidx = t >> 6;
    int dt2 = fidx & 1; (void)dt2;
    int nk = (fidx >> 1) & 3, nb = (fidx >> 3) & 31, hb = fidx >> 8;
    int n = nb * 64 + nk * 16 + ((lane >> 5) << 3);
    bf16x8 v = *(const bf16x8*)(VSu + (size_t)t * 8);
    const float* r0 = RSp  + (size_t)hb * N_DIM + n;
    const float* r1 = r0 + (size_t)HB * N_DIM;
    const float* r2 = RSpW + (size_t)hb * N_DIM + n;
    const float* r3 = r2 + (size_t)HB * N_DIM;
    bf16x8 o;
#pragma unroll
    for (int j = 0; j < 8; ++j)
        o[j] = f2bf(bf2f(v[j]) / ((r0[j] + r1[j]) + (r2[j] + r3[j])));
    *(bf16x8*)(VS + (size_t)t * 8) = o;
}

// ---------------------------------------------------------------------------
// attnout: PA_z[hb,m,d] (bf16) = sum_{n in half z} exp2(Q'.K) Vsc[n,d]
// ROUND 7 (resubmit; round-7 bench was an infra failure, no data): R5
// structure (mm=1, best measured) with __launch_bounds__(256,4): the
// compiler must fit <=128 unified regs/wave (arch ~60 + acc ~64).
// Diagnosis: all prior structures had ~190 unified regs/wave -> only 2
// barrier-phase-locked waves/SIMD -> MFMA (13.5us) and VALU (18us) pipes
// fully serialized + ~13us idle. 4 blocks/CU x 4 waves = 4 waves/SIMD from
// FOUR independent blocks -> phase diversity -> pipe overlap.
// LDS 34816 x 4 = 139KB <= 160KB. Grid 1024 = exactly 4 blocks/CU.
// Falsifier: VGPR_Count > 70 or scratch > 0 => allocator spilled.
// ---------------------------------------------------------------------------
__global__ __launch_bounds__(256, 4) void attnout_mfma(
    const short* __restrict__ QS, const short* __restrict__ KS,
    const short* __restrict__ VS,
    short* __restrict__ PA0, short* __restrict__ PA1)
{
    const int id = blockIdx.x;                     // 1024 blocks
    const int hb = ((id & 7) << 2) | ((id >> 3) & 3);
    const int z = (id >> 5) & 1;
    const int m0 = (id >> 6) * 128;                // 16 m-tiles

    // [0,16K): Q dbuf  [16K,32K): V dbuf ; epilogue T[128][68] f32 overlays
    __shared__ __align__(16) char smem[34816];
    char* Qst = smem;
    char* Vst = smem + 16384;

    const int t = threadIdx.x, wave = t >> 6, lane = t & 63;
    f32x16 czero16;
#pragma unroll
    for (int r = 0; r < 16; ++r) czero16[r] = 0.f;

    // K fragments: wave's 32 m-rows = m0 + wave*32 + (lane&31)
    bf16x8 kf[4];
    {
        const short* kbase = KS + ((size_t)(hb * 64 + (m0 >> 5) + wave)) * 4 * 512 + lane * 8;
#pragma unroll
        for (int ks = 0; ks < 4; ++ks)
            kf[ks] = *(const bf16x8*)(kbase + ks * 512);
    }

    f32x16 oacc[2];
#pragma unroll
    for (int dt2 = 0; dt2 < 2; ++dt2) oacc[dt2] = czero16;

    const short* qsrc = QS + ((size_t)(hb * 64 + z * 32)) * 4 * 512 + lane * 8;
    const short* vsrc = VS + ((size_t)(hb * 32 + z * 16)) * 8 * 512 + lane * 8;
    const int NIT = N_DIM / 2 / 64;   // 16

    f32x16 c[2];                      // E' for the current iteration (2 n-tiles)
    bf16x8 pa[4];                     // PV A-frags (4 n-chunks of 16)

    // ---- prologue: stage Q(0)->Qb0, Q(1)->Qb1, V(0)->Vb0 ----
    gll16(qsrc + (size_t)wave * 512,            Qst + wave * 1024, lane);
    gll16(qsrc + (size_t)(wave + 4) * 512,      Qst + (wave + 4) * 1024, lane);
    gll16(qsrc + (size_t)(8 + wave) * 512,      Qst + 8192 + wave * 1024, lane);
    gll16(qsrc + (size_t)(8 + wave + 4) * 512,  Qst + 8192 + (wave + 4) * 1024, lane);
    gll16(vsrc + (size_t)wave * 512,            Vst + wave * 1024, lane);
    gll16(vsrc + (size_t)(wave + 4) * 512,      Vst + (wave + 4) * 1024, lane);
    __syncthreads();                  // stages published (barrier drains vmcnt)
#pragma unroll
    for (int tt = 0; tt < 2; ++tt) {
        f32x16 cc = czero16;
#pragma unroll
        for (int ks = 0; ks < 4; ++ks) {
            bf16x8 a = *(const bf16x8*)(Qst + (tt * 4 + ks) * 1024 + lane * 16);
            cc = MFMA32(a, kf[ks], cc);
        }
        c[tt] = cc;
    }
    __syncthreads();                  // QK(0) reads of Qb0 done before restage

    for (int i = 0; i < NIT - 1; ++i) {
        // ---- stage Q(i+2) -> Qbuf[i&1], V(i+1) -> Vbuf[(i+1)&1] ----
        gll16(qsrc + ((size_t)(i + 2) * 8 + wave) * 512,
              Qst + (i & 1) * 8192 + wave * 1024, lane);
        gll16(qsrc + ((size_t)(i + 2) * 8 + wave + 4) * 512,
              Qst + (i & 1) * 8192 + (wave + 4) * 1024, lane);
        gll16(vsrc + ((size_t)(i + 1) * 8 + wave) * 512,
              Vst + ((i + 1) & 1) * 8192 + wave * 1024, lane);
        gll16(vsrc + ((size_t)(i + 1) * 8 + wave + 4) * 512,
              Vst + ((i + 1) & 1) * 8192 + (wave + 4) * 1024, lane);
        // ---- softmax-pack(i): c -> pa (exp2 + cvt_pk + permlane, no LDS) ----
#pragma unroll
        for (int tt = 0; tt < 2; ++tt) {
#pragma unroll
            for (int half = 0; half < 2; ++half) {
                unsigned w01 = pk_bf16(fx2(c[tt][half * 8 + 0]), fx2(c[tt][half * 8 + 1]));
                unsigned w23 = pk_bf16(fx2(c[tt][half * 8 + 2]), fx2(c[tt][half * 8 + 3]));
                unsigned w45 = pk_bf16(fx2(c[tt][half * 8 + 4]), fx2(c[tt][half * 8 + 5]));
                unsigned w67 = pk_bf16(fx2(c[tt][half * 8 + 6]), fx2(c[tt][half * 8 + 7]));
                pl32swap(w01, w45);
                pl32swap(w23, w67);
                u32x4 f = {w01, w23, w45, w67};
                pa[tt * 2 + half] = __builtin_bit_cast(bf16x8, f);
            }
        }
        // ---- QK(i+1) from Qbuf[(i+1)&1] ----
        {
            const char* Qb = Qst + ((i + 1) & 1) * 8192;
            __builtin_amdgcn_s_setprio(1);
#pragma unroll
            for (int tt = 0; tt < 2; ++tt) {
                f32x16 cc = czero16;
#pragma unroll
                for (int ks = 0; ks < 4; ++ks) {
                    bf16x8 a = *(const bf16x8*)(Qb + (tt * 4 + ks) * 1024 + lane * 16);
                    cc = MFMA32(a, kf[ks], cc);
                }
                c[tt] = cc;
            }
            __builtin_amdgcn_s_setprio(0);
        }
        // ---- PV(i): pa (registers) x V from Vbuf[i&1] ----
        {
            const char* vb = Vst + (i & 1) * 8192;
#pragma unroll
            for (int nk = 0; nk < 4; ++nk)
#pragma unroll
                for (int dt2 = 0; dt2 < 2; ++dt2) {
                    bf16x8 bv = *(const bf16x8*)(vb + (nk * 2 + dt2) * 1024 + lane * 16);
                    oacc[dt2] = MFMA32(pa[nk], bv, oacc[dt2]);
                }
        }
        __syncthreads();              // publish stages; retire this iter's reads
    }

    // ---- tail: softmax-pack(NIT-1) + PV(NIT-1) ----
#pragma unroll
    for (int tt = 0; tt < 2; ++tt) {
#pragma unroll
        for (int half = 0; half < 2; ++half) {
            unsigned w01 = pk_bf16(fx2(c[tt][half * 8 + 0]), fx2(c[tt][half * 8 + 1]));
            unsigned w23 = pk_bf16(fx2(c[tt][half * 8 + 2]), fx2(c[tt][half * 8 + 3]));
            unsigned w45 = pk_bf16(fx2(c[tt][half * 8 + 4]), fx2(c[tt][half * 8 + 5]));
            unsigned w67 = pk_bf16(fx2(c[tt][half * 8 + 6]), fx2(c[tt][half * 8 + 7]));
            pl32swap(w01, w45);
            pl32swap(w23, w67);
            u32x4 f = {w01, w23, w45, w67};
            pa[tt * 2 + half] = __builtin_bit_cast(bf16x8, f);
        }
    }
    {
        const char* vb = Vst + ((NIT - 1) & 1) * 8192;
#pragma unroll
        for (int nk = 0; nk < 4; ++nk)
#pragma unroll
            for (int dt2 = 0; dt2 < 2; ++dt2) {
                bf16x8 bv = *(const bf16x8*)(vb + (nk * 2 + dt2) * 1024 + lane * 16);
                oacc[dt2] = MFMA32(pa[nk], bv, oacc[dt2]);
            }
    }

    // ---- epilogue: LDS transpose (T overlays stage bufs) -> coalesced stores ----
    // PV C-layout: O[m = wave*32 + (r&3)+8*(r>>2)+4*hi][d = dt2*32 + (lane&31)]
    short* PA = z ? PA1 : PA0;
    float* T = (float*)smem;                      // [128][68] fp32
    const int hi = lane >> 5;
    __syncthreads();                              // all stage-buf reads done
#pragma unroll
    for (int dt2 = 0; dt2 < 2; ++dt2)
#pragma unroll
        for (int r = 0; r < 16; ++r) {
            int row = wave * 32 + (r & 3) + 8 * (r >> 2) + 4 * hi;
            T[row * 68 + dt2 * 32 + (lane & 31)] = oacc[dt2][r];
        }
    __syncthreads();
#pragma unroll
    for (int it = 0; it < 4; ++it) {
        int idx = it * 256 + t;                   // 0..1023
        int rowl = idx >> 3, dg = (idx & 7) * 8;  // rowl 0..127
        float4 f0 = *(const float4*)(T + rowl * 68 + dg);
        float4 f1 = *(const float4*)(T + rowl * 68 + dg + 4);
        uint4 o;
        o.x = pk_bf16(f0.x, f0.y);
        o.y = pk_bf16(f0.z, f0.w);
        o.z = pk_bf16(f1.x, f1.y);
        o.w = pk_bf16(f1.z, f1.w);
        int m = m0 + rowl;
        *(uint4*)(PA + ((size_t)(hb * N_DIM + m)) * 64 + dg) = o;
    }
}

// ---------------------------------------------------------------------------
// out = g/(1+g) * (PA0 + PA1) + YP/(1+g)
// ---------------------------------------------------------------------------
__global__ __launch_bounds__(256) void combine_out(
    const short* __restrict__ PA0, const short* __restrict__ PA1,
    const float* __restrict__ YP, const float* __restrict__ gamma,
    float* __restrict__ out)
{
    size_t flat = ((size_t)blockIdx.x * 256 + threadIdx.x) * 8;
    int d  = (int)(flat & 63);
    int n  = (int)((flat >> 6) & (N_DIM - 1));
    int hb = (int)(flat >> 17);
    int h = hb >> 2, b = hb & 3;
    float g = gamma[h];
    float inv = 1.f / (1.f + g);
    float gi = g * inv;
    bf16x8 p0 = *(const bf16x8*)(PA0 + flat);
    bf16x8 p1 = *(const bf16x8*)(PA1 + flat);
    const float* yp = YP + ((size_t)b * N_DIM + n) * HD + d;
    float o[8];
#pragma unroll
    for (int j = 0; j < 8; ++j)
        o[j] = gi * (bf2f(p0[j]) + bf2f(p1[j])) + inv * yp[j];
    float4 o0 = {o[0], o[1], o[2], o[3]};
    float4 o1 = {o[4], o[5], o[6], o[7]};
    *(float4*)(out + flat) = o0;
    *(float4*)(out + flat + 4) = o1;
}

// ---------------------------------------------------------------------------
extern "C" void kernel_launch(void* const* d_in, const int* in_sizes, int n_in,
                              void* d_out, int out_size, void* d_ws, size_t ws_size,
                              hipStream_t stream) {
    const float* x     = (const float*)d_in[0];
    const float* y     = (const float*)d_in[1];
    const float* Wq    = (const float*)d_in[2];
    const float* bq    = (const float*)d_in[3];
    const float* Wk    = (const float*)d_in[4];
    const float* bk    = (const float*)d_in[5];
    const float* Wv    = (const float*)d_in[6];
    const float* bv    = (const float*)d_in[7];
    const float* Wp    = (const float*)d_in[8];
    const float* gamma = (const float*)d_in[9];
    float* out = (float*)d_out;

    const size_t XEL  = (size_t)B_DIM * C_DIM * N_DIM;  // 2,097,152
    const size_t QKV  = (size_t)HB * N_DIM * HD;        // 4,194,304

    short* XS  = (short*)d_ws;
    short* YS  = XS + XEL;
    short* WSx = YS + XEL;            // 512*256
    short* WSy = WSx + 512 * C_DIM;   // 1088*256
    short* QS  = WSy + 1088 * C_DIM;
    short* KS  = QS + QKV;
    short* VSu = KS + QKV;
    short* VS  = VSu + QKV;
    float* YPb = (float*)(VS + QKV);
    float* RSp = YPb + (size_t)B_DIM * N_DIM * HD;      // 2 * HB * N (quarters 0,1)
    // overlays (dead after their producers/consumers finish):
    short* PA0 = XS;                  // XS+YS region = exactly QKV shorts
    short* PA1 = VSu;                 // VSu dead after v_scale
    float* RSpW = (float*)WSx;        // quarters 2,3: weight region dead after proj_all
                                      // (needs 512 KB; WSx+WSy = 800 KB)

    dim3 blk(256);
    cast_all<<<dim3(N_DIM / 64, C_DIM / 64, 9), blk, 0, stream>>>(
        x, y, Wq, Wk, Wv, Wp, XS, YS, WSx, WSy);

    proj_all<<<dim3(NTOK / 128, 25), blk, 0, stream>>>(
        WSx, WSy, XS, YS, bq, bk, bv, QS, KS, VSu, YPb);

    rowsum_mfma<<<dim3(1024), blk, 0, stream>>>(QS, KS, RSp, RSpW);
    v_scale<<<dim3(2048), blk, 0, stream>>>(VSu, RSp, RSpW, VS);
    attnout_mfma<<<dim3(1024), blk, 0, stream>>>(QS, KS, VS, PA0, PA1);
    combine_out<<<dim3(2048), blk, 0, stream>>>(PA0, PA1, YPb, gamma, out);
}

// Round 9
// 176.345 us; speedup vs baseline: 1.0871x; 1.0871x over previous
//
#include <hip/hip_runtime.h>
#include <math.h>
#include <stdint.h>

#define B_DIM 4
#define C_DIM 256
#define N_DIM 2048
#define H_DIM 8
#define HD    64
#define HB    32                 // H*B
#define NTOK  (B_DIM * N_DIM)    // 8192
#define LOG2E 1.44269504f

typedef __attribute__((ext_vector_type(8))) short bf16x8;
typedef __attribute__((ext_vector_type(4))) float f32x4;
typedef __attribute__((ext_vector_type(16))) float f32x16;
typedef __attribute__((ext_vector_type(4))) unsigned u32x4;

static __device__ __forceinline__ short f2bf(float f) {          // RNE (cold paths)
    unsigned u = __builtin_bit_cast(unsigned, f);
    u += 0x7fffu + ((u >> 16) & 1u);
    return (short)(u >> 16);
}
static __device__ __forceinline__ float bf2f(short s) {
    unsigned u = ((unsigned)(unsigned short)s) << 16;
    return __builtin_bit_cast(float, u);
}
// raw v_exp_f32: exact for |x| <~ 126, skips OCML's range-guard sequence
static __device__ __forceinline__ float fx2(float x) {
#if __has_builtin(__builtin_amdgcn_exp2f)
    return __builtin_amdgcn_exp2f(x);
#else
    return exp2f(x);
#endif
}
// pack two fp32 -> two bf16 in one dword (HW packed cvt when available)
static __device__ __forceinline__ unsigned pk_bf16(float a, float b) {
#if __has_builtin(__builtin_amdgcn_cvt_pk_bf16_f32)
    auto v = __builtin_amdgcn_cvt_pk_bf16_f32(a, b);
    return __builtin_bit_cast(unsigned, v);
#else
    unsigned ua = __builtin_bit_cast(unsigned, a);
    unsigned ub = __builtin_bit_cast(unsigned, b);
    return ((ua + 0x8000u) >> 16) | ((ub + 0x8000u) & 0xffff0000u);
#endif
}
// permlane32_swap "unzip": a' = {a.lo | b.lo-in-hi}, b' = {a.hi-in-lo | b.hi}
static __device__ __forceinline__ void pl32swap(unsigned &a, unsigned &b) {
#if __has_builtin(__builtin_amdgcn_permlane32_swap)
    typedef __attribute__((ext_vector_type(2))) int i32x2_t;
    i32x2_t r = __builtin_amdgcn_permlane32_swap((int)a, (int)b, false, false);
    a = (unsigned)r[0]; b = (unsigned)r[1];
#else
    unsigned sa = __shfl_xor(a, 32), sb = __shfl_xor(b, 32);
    bool hi = (threadIdx.x & 32) != 0;
    unsigned na = hi ? sb : a;
    unsigned nb = hi ? b : sa;
    a = na; b = nb;
#endif
}

// async global->LDS 16B/lane: dest = wave-uniform LDS base + lane*16,
// src = per-lane global address. Fallback: plain reg round-trip.
static __device__ __forceinline__ void gll16(const void* g, void* ldsbase, int lane) {
#if __has_builtin(__builtin_amdgcn_global_load_lds)
    __builtin_amdgcn_global_load_lds(
        (const __attribute__((address_space(1))) void*)(uintptr_t)(g),
        (__attribute__((address_space(3))) void*)(uintptr_t)(ldsbase), 16, 0, 0);
#else
    *(bf16x8*)((char*)ldsbase + lane * 16) = *(const bf16x8*)g;
#endif
}

#define MFMA16(A, Bv, Cv) __builtin_amdgcn_mfma_f32_16x16x32_bf16(A, Bv, Cv, 0, 0, 0)
#define MFMA32(A, Bv, Cv) __builtin_amdgcn_mfma_f32_32x32x16_bf16(A, Bv, Cv, 0, 0, 0)

// 16x16 fragment layouts (proj_all staging, unchanged):
//   XS/YS(rt, ks, lane, j) = X[tok = rt*16+(lane&15)][c = ks*32+(lane>>4)*8+j]
//   WS(ot, ks, lane, j)    = W[o  = ot*16+(lane&15)][c = ks*32+(lane>>4)*8+j]
// 32x32x16 fragment layouts (attention kernels; frag = 1 KB, row=lane&31,
// k = (lane>>5)*8 + j):
//   QS/KS frag(hb, nt2, ks): M[n = nt2*32+(lane&31)][d = ks*16+(lane>>5)*8+j]
//     (QS holds Q * log2e); frag index = (hb*64 + nt2)*4 + ks
//   VS frag(hb, nb, nk, dt2): V[d = dt2*32+(lane&31)][n = nb*64+nk*16+(lane>>5)*8+j]
//     frag index = ((hb*32 + nb)*4 + nk)*2 + dt2

// ---------------------------------------------------------------------------
// cast+transpose to fragment-major (z 0..7: x/y batches) + weights (z == 8)
// ---------------------------------------------------------------------------
__global__ __launch_bounds__(256) void cast_all(
    const float* __restrict__ X, const float* __restrict__ Y,
    const float* __restrict__ Wq, const float* __restrict__ Wk,
    const float* __restrict__ Wv, const float* __restrict__ Wp,
    short* __restrict__ XS, short* __restrict__ YS,
    short* __restrict__ WSx, short* __restrict__ WSy)
{
    const int z = blockIdx.z;
    const int t = threadIdx.x;

    if (z == 8) {   // ---- weights: Wq -> WSx (256 chunks); Wk|Wv|Wp -> WSy (544) ----
        int base = (blockIdx.y * 32 + blockIdx.x) * 256 + t;   // 0..32767
#pragma unroll
        for (int rep = 0; rep < 2; ++rep) {
            int gid = base + rep * 32768;                       // 0..65535
            if (gid >= 51200) break;
            int lane = gid & 63, chunk = gid >> 6;              // chunk 0..799
            int lo = lane & 15, quad = lane >> 4;
            const float* src; short* dst;
            if (chunk < 256) {
                int ot = chunk >> 3, ks = chunk & 7;
                src = Wq + (size_t)(ot * 16 + lo) * C_DIM + ks * 32 + quad * 8;
                dst = WSx + (size_t)chunk * 512 + lane * 8;
            } else {
                int ch = chunk - 256;
                int ot = ch >> 3, ks = ch & 7;
                int row = ot * 16 + lo;
                const float* basep = (row < 512) ? (Wk + (size_t)row * C_DIM)
                                   : (row < 1024) ? (Wv + (size_t)(row - 512) * C_DIM)
                                                  : (Wp + (size_t)(row - 1024) * C_DIM);
                src = basep + ks * 32 + quad * 8;
                dst = WSy + (size_t)ch * 512 + lane * 8;
            }
            bf16x8 o;
#pragma unroll
            for (int j = 0; j < 8; ++j) o[j] = f2bf(src[j]);
            *(bf16x8*)dst = o;
        }
        return;
    }

    const float* src = (z < 4) ? X : Y;
    short* dst = (z < 4) ? XS : YS;
    const int b = z & 3, c0 = blockIdx.y * 64, n0 = blockIdx.x * 64;
    __shared__ float L[64][65];   // [c_local][n_local]
    for (int i = t; i < 4096; i += 256) {
        int cc = i >> 6, nn = i & 63;
        L[cc][nn] = src[((size_t)b * C_DIM + c0 + cc) * N_DIM + n0 + nn];
    }
    __syncthreads();
#pragma unroll
    for (int half = 0; half < 2; ++half) {
        int cid = half * 256 + t;
        int lane = cid & 63, fi = cid >> 6;      // fi 0..7
        int ksl = fi & 1, rtl = fi >> 1;         // rtl 0..3
        int lo = lane & 15, quad = lane >> 4;
        bf16x8 o;
#pragma unroll
        for (int j = 0; j < 8; ++j) o[j] = f2bf(L[ksl * 32 + quad * 8 + j][rtl * 16 + lo]);
        int rt = b * 128 + (n0 >> 4) + rtl;
        int ks = (c0 >> 5) + ksl;
        *(bf16x8*)(dst + ((size_t)(rt * 8 + ks) * 64 + lane) * 8) = o;
    }
}

// ---------------------------------------------------------------------------
// Merged MFMA projection (16x16 MFMA internally).
// ROUND 9: the 8 nt x 8 ks Xs fragments (64 KB) were read REDUNDANTLY by all
// 4 waves from L2 (288 KB/block x 1600 blocks ~ 410 MB -> L2-BW-bound).
// Now staged ONCE per block into LDS via global_load_lds (16 frags/wave),
// one barrier, MFMA loop reads from LDS. W frags stay direct (wave-specific).
// LDS: XL 64 KB overlaid with epilogue T (extra barrier before T writes).
// oy<8: Q -> QS32. oy 8..15: K -> KS32. oy 16..23: V -> VS32u. oy==24: YP.
// ---------------------------------------------------------------------------
__global__ __launch_bounds__(256) void proj_all(
    const short* __restrict__ WSx, const short* __restrict__ WSy,
    const short* __restrict__ XS, const short* __restrict__ YS,
    const float* __restrict__ bq, const float* __restrict__ bk,
    const float* __restrict__ bv,
    short* __restrict__ QS, short* __restrict__ KS,
    short* __restrict__ VSu, float* __restrict__ Yo)
{
    const int oy = blockIdx.y;
    const bool isq = oy < 8;
    const short* WS = isq ? WSx : WSy;
    const short* Xs = isq ? XS : YS;
    const int oyl = isq ? oy : oy - 8;
    const int o0 = oyl * 64;
    const int tok0 = blockIdx.x * 128;
    const int t = threadIdx.x, wave = t >> 6, lane = t & 63;
    const int lo = lane & 15, quad = lane >> 4;

    __shared__ __align__(16) char smem[65536];    // XL (64 KB) / epilogue T overlay
    char* XL = smem;

    const int ot = oyl * 4 + wave;
    const int rt0 = tok0 >> 4;
    const f32x4 czero = {0.f, 0.f, 0.f, 0.f};

    // ---- stage all 64 Xs fragments for this token tile (16 per wave) ----
    {
        const short* xsl = Xs + lane * 8;
#pragma unroll
        for (int f = 0; f < 16; ++f) {
            int l = wave * 16 + f;                // frag l = nt*8 + ks
            int nt = l >> 3, ks = l & 7;
            gll16(xsl + (size_t)((rt0 + nt) * 8 + ks) * 512, XL + l * 1024, lane);
        }
    }

    f32x4 acc[8];
#pragma unroll
    for (int i = 0; i < 8; ++i) acc[i] = czero;

    __syncthreads();                              // XL staged (barrier drains vmcnt)

#pragma unroll 2
    for (int ks = 0; ks < 8; ++ks) {
        bf16x8 a = *(const bf16x8*)(WS + ((size_t)(ot * 8 + ks) * 64 + lane) * 8);
#pragma unroll
        for (int nt = 0; nt < 8; ++nt) {
            bf16x8 bx = *(const bf16x8*)(XL + (nt * 8 + ks) * 1024 + lane * 16);
            acc[nt] = MFMA16(a, bx, acc[nt]);
        }
    }

    __syncthreads();                              // all XL reads done before T overlay

    const int b = tok0 >> 11;
    const int n0b = tok0 & (N_DIM - 1);

    if (oy < 16) {
        // ---- Q or K: T[128][72] bf16 -> 32x32 fragment-major QS/KS ----
        short* T = (short*)smem;
        const float* bias = isq ? bq : bk;
        const float scale = isq ? LOG2E : 1.f;
        float bvr[4];
#pragma unroll
        for (int r = 0; r < 4; ++r) bvr[r] = bias[o0 + wave * 16 + quad * 4 + r];
#pragma unroll
        for (int nt = 0; nt < 8; ++nt) {
            short4 pk;
            pk.x = f2bf((acc[nt][0] + bvr[0]) * scale);
            pk.y = f2bf((acc[nt][1] + bvr[1]) * scale);
            pk.z = f2bf((acc[nt][2] + bvr[2]) * scale);
            pk.w = f2bf((acc[nt][3] + bvr[3]) * scale);
            *(short4*)(T + (nt * 16 + lo) * 72 + wave * 16 + quad * 4) = pk;
        }
        __syncthreads();
        const int h = oyl;
        const int hb = h * 4 + b;
        short* dst = isq ? QS : KS;
#pragma unroll
        for (int s = 0; s < 4; ++s) {
            int cid = s * 256 + t;
            int ln = cid & 63, fi = cid >> 6;     // fi 0..15
            int ks = fi & 3, nt2l = fi >> 2;      // 4 d-chunks x 4 n-tiles
            bf16x8 v = *(const bf16x8*)(T + (nt2l * 32 + (ln & 31)) * 72
                                          + ks * 16 + ((ln >> 5) << 3));
            size_t frag = ((size_t)(hb * 64) + (n0b >> 5) + nt2l) * 4 + ks;
            *(bf16x8*)(dst + frag * 512 + ln * 8) = v;
        }
    } else if (oy < 24) {
        // ---- V: T2[64][136] bf16 (d-major) -> 32x32 fragment-major VSu ----
        short* T2 = (short*)smem;
        float bvr[4];
#pragma unroll
        for (int r = 0; r < 4; ++r) bvr[r] = bv[o0 - 512 + wave * 16 + quad * 4 + r];
#pragma unroll
        for (int nt = 0; nt < 8; ++nt)
#pragma unroll
            for (int r = 0; r < 4; ++r) {
                int ol = wave * 16 + quad * 4 + r;
                T2[ol * 136 + nt * 16 + lo] = f2bf(acc[nt][r] + bvr[r]);
            }
        __syncthreads();
        const int h = oy - 16;
        const int hb = h * 4 + b;
#pragma unroll
        for (int s = 0; s < 4; ++s) {
            int cid = s * 256 + t;
            int ln = cid & 63, fi = cid >> 6;     // fi 0..15
            int dt2 = fi & 1, nk = (fi >> 1) & 3, nbl = fi >> 3;
            bf16x8 v = *(const bf16x8*)(T2 + (dt2 * 32 + (ln & 31)) * 136
                                           + nbl * 64 + nk * 16 + ((ln >> 5) << 3));
            size_t frag = (((size_t)(hb * 32) + (n0b >> 6) + nbl) * 4 + nk) * 2 + dt2;
            *(bf16x8*)(VSu + frag * 512 + ln * 8) = v;
        }
    } else {
        // ---- YP: T3[128][68] fp32 -> (b,n,d) float4 stores ----
        float* T3 = (float*)smem;
#pragma unroll
        for (int nt = 0; nt < 8; ++nt) {
            float4 f;
            f.x = acc[nt][0]; f.y = acc[nt][1]; f.z = acc[nt][2]; f.w = acc[nt][3];
            *(float4*)(T3 + (nt * 16 + lo) * 68 + wave * 16 + quad * 4) = f;
        }
        __syncthreads();
#pragma unroll
        for (int s = 0; s < 8; ++s) {
            int cid = s * 256 + t;
            int row = cid >> 4, c4 = (cid & 15) * 4;
            float4 f = *(const float4*)(T3 + row * 68 + c4);
            *(float4*)(Yo + ((size_t)(tok0 + row)) * 64 + c4) = f;
        }
    }
}

// ---------------------------------------------------------------------------
// rowsum partials over m-QUARTERS, 32x32x16 MFMA, register-only (no LDS).
// Wave owns 64 n (8 Q frags resident); streams K m-tiles from L2.
// 1024 blocks x 256 thr. Quarters 0,1 -> RSp; 2,3 -> RSpW (weight overlay).
// ---------------------------------------------------------------------------
__global__ __launch_bounds__(256, 4) void rowsum_mfma(
    const short* __restrict__ QS, const short* __restrict__ KS,
    float* __restrict__ RSp, float* __restrict__ RSpW)
{
    const int id = blockIdx.x;                     // 1024 blocks
    const int hb = ((id & 7) << 2) | ((id >> 3) & 3);   // h = id&7 -> XCD L2 locality
    const int zq = (id >> 5) & 3;                  // m-quarter
    const int n0 = (id >> 7) * 256;                // 8 n-tiles
    const int t = threadIdx.x, wave = t >> 6, lane = t & 63;
    const int hi = lane >> 5;
    f32x16 czero16;
#pragma unroll
    for (int r = 0; r < 16; ++r) czero16[r] = 0.f;

    bf16x8 qf[2][4];
    const short* qb = QS + ((size_t)(hb * 64 + (n0 >> 5) + wave * 2)) * 4 * 512 + lane * 8;
#pragma unroll
    for (int tt = 0; tt < 2; ++tt)
#pragma unroll
        for (int ks = 0; ks < 4; ++ks)
            qf[tt][ks] = *(const bf16x8*)(qb + (tt * 4 + ks) * 512);

    float sm[2][16];
#pragma unroll
    for (int tt = 0; tt < 2; ++tt)
#pragma unroll
        for (int r = 0; r < 16; ++r) sm[tt][r] = 0.f;

    const short* kp = KS + ((size_t)(hb * 64 + zq * 16)) * 4 * 512 + lane * 8;
    for (int mt = 0; mt < 16; ++mt) {
        bf16x8 kf[4];
#pragma unroll
        for (int ks = 0; ks < 4; ++ks)
            kf[ks] = *(const bf16x8*)(kp + (mt * 4 + ks) * 512);
#pragma unroll
        for (int tt = 0; tt < 2; ++tt) {
            f32x16 cc = czero16;
#pragma unroll
            for (int ks = 0; ks < 4; ++ks) cc = MFMA32(qf[tt][ks], kf[ks], cc);
#pragma unroll
            for (int r = 0; r < 16; ++r) sm[tt][r] += fx2(cc[r]);
        }
    }

#pragma unroll
    for (int sft = 1; sft < 32; sft <<= 1)
#pragma unroll
        for (int tt = 0; tt < 2; ++tt)
#pragma unroll
            for (int r = 0; r < 16; ++r) sm[tt][r] += __shfl_xor(sm[tt][r], sft);

    if ((lane & 31) == 0) {
        float* dst = (zq < 2) ? (RSp  + (size_t)zq * HB * N_DIM)
                              : (RSpW + (size_t)(zq - 2) * HB * N_DIM);
#pragma unroll
        for (int tt = 0; tt < 2; ++tt)
#pragma unroll
            for (int g = 0; g < 4; ++g) {
                int n = n0 + wave * 64 + tt * 32 + g * 8 + hi * 4;
                float4 v = {sm[tt][g * 4 + 0], sm[tt][g * 4 + 1],
                            sm[tt][g * 4 + 2], sm[tt][g * 4 + 3]};
                *(float4*)(dst + (size_t)hb * N_DIM + n) = v;
            }
    }
}

// ---------------------------------------------------------------------------
// VS = VSu * 1/(sum of 4 rowsum partials) — 32x32 fragment layout in/out
// ---------------------------------------------------------------------------
__global__ __launch_bounds__(256) void v_scale(
    const short* __restrict__ VSu, const float* __restrict__ RSp,
    const float* __restrict__ RSpW, short* __restrict__ VS)
{
    int t = blockIdx.x * 256 + threadIdx.x;     // 0..524287
    int lane = t & 63, fidx = t >> 6;
    int dt2 = fidx & 1; (void)dt2;
    int nk = (fidx >> 1) & 3, nb = (fidx >> 3) & 31, hb = fidx >> 8;
    int n = nb * 64 + nk * 16 + ((lane >> 5) << 3);
    bf16x8 v = *(const bf16x8*)(VSu + (size_t)t * 8);
    const float* r0 = RSp  + (size_t)hb * N_DIM + n;
    const float* r1 = r0 + (size_t)HB * N_DIM;
    const float* r2 = RSpW + (size_t)hb * N_DIM + n;
    const float* r3 = r2 + (size_t)HB * N_DIM;
    bf16x8 o;
#pragma unroll
    for (int j = 0; j < 8; ++j)
        o[j] = f2bf(bf2f(v[j]) / ((r0[j] + r1[j]) + (r2[j] + r3[j])));
    *(bf16x8*)(VS + (size_t)t * 8) = o;
}

// ---------------------------------------------------------------------------
// attnout: PA_z[hb,m,d] (bf16) = sum_{n in half z} exp2(Q'.K) Vsc[n,d]
// FROZEN at the round-8 variant (44 us measured): 32x32x16 MFMA, P in
// registers (cvt_pk+permlane32, T12), Q/V global_load_lds double buffers,
// launch_bounds(256,4). attnout is ~23% of wall; round 9 targets the rest.
// ---------------------------------------------------------------------------
__global__ __launch_bounds__(256, 4) void attnout_mfma(
    const short* __restrict__ QS, const short* __restrict__ KS,
    const short* __restrict__ VS,
    short* __restrict__ PA0, short* __restrict__ PA1)
{
    const int id = blockIdx.x;                     // 1024 blocks
    const int hb = ((id & 7) << 2) | ((id >> 3) & 3);
    const int z = (id >> 5) & 1;
    const int m0 = (id >> 6) * 128;                // 16 m-tiles

    // [0,16K): Q dbuf  [16K,32K): V dbuf ; epilogue T[128][68] f32 overlays
    __shared__ __align__(16) char smem[34816];
    char* Qst = smem;
    char* Vst = smem + 16384;

    const int t = threadIdx.x, wave = t >> 6, lane = t & 63;
    f32x16 czero16;
#pragma unroll
    for (int r = 0; r < 16; ++r) czero16[r] = 0.f;

    // K fragments: wave's 32 m-rows = m0 + wave*32 + (lane&31)
    bf16x8 kf[4];
    {
        const short* kbase = KS + ((size_t)(hb * 64 + (m0 >> 5) + wave)) * 4 * 512 + lane * 8;
#pragma unroll
        for (int ks = 0; ks < 4; ++ks)
            kf[ks] = *(const bf16x8*)(kbase + ks * 512);
    }

    f32x16 oacc[2];
#pragma unroll
    for (int dt2 = 0; dt2 < 2; ++dt2) oacc[dt2] = czero16;

    const short* qsrc = QS + ((size_t)(hb * 64 + z * 32)) * 4 * 512 + lane * 8;
    const short* vsrc = VS + ((size_t)(hb * 32 + z * 16)) * 8 * 512 + lane * 8;
    const int NIT = N_DIM / 2 / 64;   // 16

    f32x16 c[2];                      // E' for the current iteration (2 n-tiles)
    bf16x8 pa[4];                     // PV A-frags (4 n-chunks of 16)

    // ---- prologue: stage Q(0)->Qb0, Q(1)->Qb1, V(0)->Vb0 ----
    gll16(qsrc + (size_t)wave * 512,            Qst + wave * 1024, lane);
    gll16(qsrc + (size_t)(wave + 4) * 512,      Qst + (wave + 4) * 1024, lane);
    gll16(qsrc + (size_t)(8 + wave) * 512,      Qst + 8192 + wave * 1024, lane);
    gll16(qsrc + (size_t)(8 + wave + 4) * 512,  Qst + 8192 + (wave + 4) * 1024, lane);
    gll16(vsrc + (size_t)wave * 512,            Vst + wave * 1024, lane);
    gll16(vsrc + (size_t)(wave + 4) * 512,      Vst + (wave + 4) * 1024, lane);
    __syncthreads();                  // stages published (barrier drains vmcnt)
#pragma unroll
    for (int tt = 0; tt < 2; ++tt) {
        f32x16 cc = czero16;
#pragma unroll
        for (int ks = 0; ks < 4; ++ks) {
            bf16x8 a = *(const bf16x8*)(Qst + (tt * 4 + ks) * 1024 + lane * 16);
            cc = MFMA32(a, kf[ks], cc);
        }
        c[tt] = cc;
    }
    __syncthreads();                  // QK(0) reads of Qb0 done before restage

    for (int i = 0; i < NIT - 1; ++i) {
        // ---- stage Q(i+2) -> Qbuf[i&1], V(i+1) -> Vbuf[(i+1)&1] ----
        gll16(qsrc + ((size_t)(i + 2) * 8 + wave) * 512,
              Qst + (i & 1) * 8192 + wave * 1024, lane);
        gll16(qsrc + ((size_t)(i + 2) * 8 + wave + 4) * 512,
              Qst + (i & 1) * 8192 + (wave + 4) * 1024, lane);
        gll16(vsrc + ((size_t)(i + 1) * 8 + wave) * 512,
              Vst + ((i + 1) & 1) * 8192 + wave * 1024, lane);
        gll16(vsrc + ((size_t)(i + 1) * 8 + wave + 4) * 512,
              Vst + ((i + 1) & 1) * 8192 + (wave + 4) * 1024, lane);
        // ---- softmax-pack(i): c -> pa (exp2 + cvt_pk + permlane, no LDS) ----
#pragma unroll
        for (int tt = 0; tt < 2; ++tt) {
#pragma unroll
            for (int half = 0; half < 2; ++half) {
                unsigned w01 = pk_bf16(fx2(c[tt][half * 8 + 0]), fx2(c[tt][half * 8 + 1]));
                unsigned w23 = pk_bf16(fx2(c[tt][half * 8 + 2]), fx2(c[tt][half * 8 + 3]));
                unsigned w45 = pk_bf16(fx2(c[tt][half * 8 + 4]), fx2(c[tt][half * 8 + 5]));
                unsigned w67 = pk_bf16(fx2(c[tt][half * 8 + 6]), fx2(c[tt][half * 8 + 7]));
                pl32swap(w01, w45);
                pl32swap(w23, w67);
                u32x4 f = {w01, w23, w45, w67};
                pa[tt * 2 + half] = __builtin_bit_cast(bf16x8, f);
            }
        }
        // ---- QK(i+1) from Qbuf[(i+1)&1] ----
        {
            const char* Qb = Qst + ((i + 1) & 1) * 8192;
            __builtin_amdgcn_s_setprio(1);
#pragma unroll
            for (int tt = 0; tt < 2; ++tt) {
                f32x16 cc = czero16;
#pragma unroll
                for (int ks = 0; ks < 4; ++ks) {
                    bf16x8 a = *(const bf16x8*)(Qb + (tt * 4 + ks) * 1024 + lane * 16);
                    cc = MFMA32(a, kf[ks], cc);
                }
                c[tt] = cc;
            }
            __builtin_amdgcn_s_setprio(0);
        }
        // ---- PV(i): pa (registers) x V from Vbuf[i&1] ----
        {
            const char* vb = Vst + (i & 1) * 8192;
#pragma unroll
            for (int nk = 0; nk < 4; ++nk)
#pragma unroll
                for (int dt2 = 0; dt2 < 2; ++dt2) {
                    bf16x8 bv = *(const bf16x8*)(vb + (nk * 2 + dt2) * 1024 + lane * 16);
                    oacc[dt2] = MFMA32(pa[nk], bv, oacc[dt2]);
                }
        }
        __syncthreads();              // publish stages; retire this iter's reads
    }

    // ---- tail: softmax-pack(NIT-1) + PV(NIT-1) ----
#pragma unroll
    for (int tt = 0; tt < 2; ++tt) {
#pragma unroll
        for (int half = 0; half < 2; ++half) {
            unsigned w01 = pk_bf16(fx2(c[tt][half * 8 + 0]), fx2(c[tt][half * 8 + 1]));
            unsigned w23 = pk_bf16(fx2(c[tt][half * 8 + 2]), fx2(c[tt][half * 8 + 3]));
            unsigned w45 = pk_bf16(fx2(c[tt][half * 8 + 4]), fx2(c[tt][half * 8 + 5]));
            unsigned w67 = pk_bf16(fx2(c[tt][half * 8 + 6]), fx2(c[tt][half * 8 + 7]));
            pl32swap(w01, w45);
            pl32swap(w23, w67);
            u32x4 f = {w01, w23, w45, w67};
            pa[tt * 2 + half] = __builtin_bit_cast(bf16x8, f);
        }
    }
    {
        const char* vb = Vst + ((NIT - 1) & 1) * 8192;
#pragma unroll
        for (int nk = 0; nk < 4; ++nk)
#pragma unroll
            for (int dt2 = 0; dt2 < 2; ++dt2) {
                bf16x8 bv = *(const bf16x8*)(vb + (nk * 2 + dt2) * 1024 + lane * 16);
                oacc[dt2] = MFMA32(pa[nk], bv, oacc[dt2]);
            }
    }

    // ---- epilogue: LDS transpose (T overlays stage bufs) -> coalesced stores ----
    // PV C-layout: O[m = wave*32 + (r&3)+8*(r>>2)+4*hi][d = dt2*32 + (lane&31)]
    short* PA = z ? PA1 : PA0;
    float* T = (float*)smem;                      // [128][68] fp32
    const int hi = lane >> 5;
    __syncthreads();                              // all stage-buf reads done
#pragma unroll
    for (int dt2 = 0; dt2 < 2; ++dt2)
#pragma unroll
        for (int r = 0; r < 16; ++r) {
            int row = wave * 32 + (r & 3) + 8 * (r >> 2) + 4 * hi;
            T[row * 68 + dt2 * 32 + (lane & 31)] = oacc[dt2][r];
        }
    __syncthreads();
#pragma unroll
    for (int it = 0; it < 4; ++it) {
        int idx = it * 256 + t;                   // 0..1023
        int rowl = idx >> 3, dg = (idx & 7) * 8;  // rowl 0..127
        float4 f0 = *(const float4*)(T + rowl * 68 + dg);
        float4 f1 = *(const float4*)(T + rowl * 68 + dg + 4);
        uint4 o;
        o.x = pk_bf16(f0.x, f0.y);
        o.y = pk_bf16(f0.z, f0.w);
        o.z = pk_bf16(f1.x, f1.y);
        o.w = pk_bf16(f1.z, f1.w);
        int m = m0 + rowl;
        *(uint4*)(PA + ((size_t)(hb * N_DIM + m)) * 64 + dg) = o;
    }
}

// ---------------------------------------------------------------------------
// out = g/(1+g) * (PA0 + PA1) + YP/(1+g)
// ---------------------------------------------------------------------------
__global__ __launch_bounds__(256) void combine_out(
    const short* __restrict__ PA0, const short* __restrict__ PA1,
    const float* __restrict__ YP, const float* __restrict__ gamma,
    float* __restrict__ out)
{
    size_t flat = ((size_t)blockIdx.x * 256 + threadIdx.x) * 8;
    int d  = (int)(flat & 63);
    int n  = (int)((flat >> 6) & (N_DIM - 1));
    int hb = (int)(flat >> 17);
    int h = hb >> 2, b = hb & 3;
    float g = gamma[h];
    float inv = 1.f / (1.f + g);
    float gi = g * inv;
    bf16x8 p0 = *(const bf16x8*)(PA0 + flat);
    bf16x8 p1 = *(const bf16x8*)(PA1 + flat);
    const float* yp = YP + ((size_t)b * N_DIM + n) * HD + d;
    float o[8];
#pragma unroll
    for (int j = 0; j < 8; ++j)
        o[j] = gi * (bf2f(p0[j]) + bf2f(p1[j])) + inv * yp[j];
    float4 o0 = {o[0], o[1], o[2], o[3]};
    float4 o1 = {o[4], o[5], o[6], o[7]};
    *(float4*)(out + flat) = o0;
    *(float4*)(out + flat + 4) = o1;
}

// ---------------------------------------------------------------------------
extern "C" void kernel_launch(void* const* d_in, const int* in_sizes, int n_in,
                              void* d_out, int out_size, void* d_ws, size_t ws_size,
                              hipStream_t stream) {
    const float* x     = (const float*)d_in[0];
    const float* y     = (const float*)d_in[1];
    const float* Wq    = (const float*)d_in[2];
    const float* bq    = (const float*)d_in[3];
    const float* Wk    = (const float*)d_in[4];
    const float* bk    = (const float*)d_in[5];
    const float* Wv    = (const float*)d_in[6];
    const float* bv    = (const float*)d_in[7];
    const float* Wp    = (const float*)d_in[8];
    const float* gamma = (const float*)d_in[9];
    float* out = (float*)d_out;

    const size_t XEL  = (size_t)B_DIM * C_DIM * N_DIM;  // 2,097,152
    const size_t QKV  = (size_t)HB * N_DIM * HD;        // 4,194,304

    short* XS  = (short*)d_ws;
    short* YS  = XS + XEL;
    short* WSx = YS + XEL;            // 512*256
    short* WSy = WSx + 512 * C_DIM;   // 1088*256
    short* QS  = WSy + 1088 * C_DIM;
    short* KS  = QS + QKV;
    short* VSu = KS + QKV;
    short* VS  = VSu + QKV;
    float* YPb = (float*)(VS + QKV);
    float* RSp = YPb + (size_t)B_DIM * N_DIM * HD;      // 2 * HB * N (quarters 0,1)
    // overlays (dead after their producers/consumers finish):
    short* PA0 = XS;                  // XS+YS region = exactly QKV shorts
    short* PA1 = VSu;                 // VSu dead after v_scale
    float* RSpW = (float*)WSx;        // quarters 2,3: weight region dead after proj_all
                                      // (needs 512 KB; WSx+WSy = 800 KB)

    dim3 blk(256);
    cast_all<<<dim3(N_DIM / 64, C_DIM / 64, 9), blk, 0, stream>>>(
        x, y, Wq, Wk, Wv, Wp, XS, YS, WSx, WSy);

    proj_all<<<dim3(NTOK / 128, 25), blk, 0, stream>>>(
        WSx, WSy, XS, YS, bq, bk, bv, QS, KS, VSu, YPb);

    rowsum_mfma<<<dim3(1024), blk, 0, stream>>>(QS, KS, RSp, RSpW);
    v_scale<<<dim3(2048), blk, 0, stream>>>(VSu, RSp, RSpW, VS);
    attnout_mfma<<<dim3(1024), blk, 0, stream>>>(QS, KS, VS, PA0, PA1);
    combine_out<<<dim3(2048), blk, 0, stream>>>(PA0, PA1, YPb, gamma, out);
}